// Round 7
// baseline (546.449 us; speedup 1.0000x reference)
//
#include <hip/hip_runtime.h>

typedef float f32x2 __attribute__((ext_vector_type(2)));
typedef float f32x4 __attribute__((ext_vector_type(4)));
typedef _Float16 h16x2 __attribute__((ext_vector_type(2)));
typedef __fp16 fp16x2_raw __attribute__((ext_vector_type(2)));

#define LOG2E 1.44269504088896340736f

static __device__ __forceinline__ float rcp_fast(float x) { return __builtin_amdgcn_rcpf(x); }

static __device__ __forceinline__ f32x2 mk2(float a, float b) { f32x2 v; v[0] = a; v[1] = b; return v; }

static __device__ __forceinline__ float sigmoid_fast(float x) {
    return rcp_fast(1.0f + __builtin_amdgcn_exp2f(-LOG2E * x));
}

static __device__ __forceinline__ float tanh_fast(float x) {
    float a = __builtin_fabsf(x);
    float t = __builtin_amdgcn_exp2f(-2.0f * LOG2E * a);
    float r = (1.0f - t) * rcp_fast(1.0f + t);
    return __builtin_copysignf(r, x);
}

static __device__ __forceinline__ float fdot2(h16x2 a, h16x2 b, float c) {
#if __has_builtin(__builtin_amdgcn_fdot2)
    return __builtin_amdgcn_fdot2(a, b, c, false);
#else
    return c + (float)(a[0]) * (float)(b[0]) + (float)(a[1]) * (float)(b[1]);
#endif
}

static __device__ __forceinline__ h16x2 pk(float a, float b) {
    fp16x2_raw r = __builtin_amdgcn_cvt_pkrtz(a, b);
    return __builtin_bit_cast(h16x2, r);
}

template <int CTRL>
static __device__ __forceinline__ int dppi(int src) {
    return __builtin_amdgcn_update_dpp(0, src, CTRL, 0xF, 0xF, true);
}

static __device__ __forceinline__ void load_pairs16(const float* p, f32x2* dst) {
    const f32x4* q4 = (const f32x4*)p;
    f32x4 a = q4[0], b = q4[1], c = q4[2], d = q4[3];
    dst[0] = __builtin_shufflevector(a, a, 0, 1);
    dst[1] = __builtin_shufflevector(a, a, 2, 3);
    dst[2] = __builtin_shufflevector(b, b, 0, 1);
    dst[3] = __builtin_shufflevector(b, b, 2, 3);
    dst[4] = __builtin_shufflevector(c, c, 0, 1);
    dst[5] = __builtin_shufflevector(c, c, 2, 3);
    dst[6] = __builtin_shufflevector(d, d, 0, 1);
    dst[7] = __builtin_shufflevector(d, d, 2, 3);
}

// DUAL-STREAM, HALF-WAVE-MIRRORED: 2048 waves (2/SIMD), each wave carries TWO
// software-interleaved recurrence streams (A: batches 4b+{0,1}, B: 4b+{2,3}),
// each mirrored across both 32-lane halves (lanes are free; dependent-issue
// latency is the bottleneck). 2 HW waves x 2 SW streams = 4 independent
// dependent-chains per SIMD vs 2 before -- the chain bubbles (~4-6 cy per
// dependent VALU op across a ~200-op serial step) are what pinned every
// previous variant at ~2700 cy/step. No structs/lambdas/runtime indexing
// (R2's scratch failure); weights are f16 pairs shared by both streams and
// PINNED via asm so the allocator cannot re-load them inside the loop.
__global__ __launch_bounds__(64, 1) void vm_kernel(
    const float* __restrict__ init_state,  // (B,1,12)
    const float* __restrict__ commands,    // (B,T,4)
    const float* __restrict__ ln_g,        // (16)
    const float* __restrict__ ln_b,        // (16)
    const float* __restrict__ W_in,        // (16,16)
    const float* __restrict__ b_in,        // (16)
    const float* __restrict__ W_ih,        // (64,16)
    const float* __restrict__ W_hh,        // (64,16)
    const float* __restrict__ b_ih,        // (64)
    const float* __restrict__ b_hh,        // (64)
    const float* __restrict__ W_out,       // (12,16)
    const float* __restrict__ b_out,       // (12)
    float* __restrict__ out,               // (B,T,12)
    int B, int T)
{
    const int lane = threadIdx.x;
    const int j = lane & 15;
    const int g = lane >> 4;
    const int gbase = (lane & 48) << 2;     // byte addr of own group's lane 0
    const bool is_state = (j < 12);
    const int bbase = blockIdx.x * 4;
    const int bA = bbase + (g & 1);         // mirrored: halves hold same data
    const int bB = bbase + 2 + (g & 1);

    // ---- preamble: gate-weight fold (identical math to verified R1/R5) ----
    f32x2 Wih[4][8], Wh32[4][8];
#pragma unroll
    for (int q = 0; q < 4; ++q) {
        load_pairs16(W_ih + (q * 16 + j) * 16, Wih[q]);
        load_pairs16(W_hh + (q * 16 + j) * 16, Wh32[q]);
    }

    f32x2 Wgx[4][8];
    float binacc[4];
#pragma unroll
    for (int q = 0; q < 4; ++q) {
        binacc[q] = 0.0f;
#pragma unroll
        for (int k2 = 0; k2 < 8; ++k2) Wgx[q][k2] = mk2(0.0f, 0.0f);
    }
#pragma unroll
    for (int m = 0; m < 16; ++m) {
        f32x2 wm[8];
        load_pairs16(W_in + m * 16, wm);
        float bm = b_in[m];
#pragma unroll
        for (int q = 0; q < 4; ++q) {
            float wim = Wih[q][m >> 1][m & 1];
            f32x2 w2 = mk2(wim, wim);
#pragma unroll
            for (int k2 = 0; k2 < 8; ++k2) Wgx[q][k2] += w2 * wm[k2];
            binacc[q] += wim * bm;
        }
    }
    float sg[4], cst[4];
    {
        f32x2 gg2[8], bt2[8];
        load_pairs16(ln_g, gg2);
        load_pairs16(ln_b, bt2);
#pragma unroll
        for (int q = 0; q < 4; ++q) {
            f32x2 ss = mk2(0.0f, 0.0f), cc = mk2(0.0f, 0.0f);
#pragma unroll
            for (int k2 = 0; k2 < 8; ++k2) {
                cc += Wgx[q][k2] * bt2[k2];
                Wgx[q][k2] *= gg2[k2];
                ss += Wgx[q][k2];
            }
            sg[q]  = ss[0] + ss[1];
            cst[q] = cc[0] + cc[1] + binacc[q] + b_ih[q * 16 + j] + b_hh[q * 16 + j];
        }
    }

    h16x2 WgxH[4][8], WhH[4][8];
#pragma unroll
    for (int q = 0; q < 4; ++q)
#pragma unroll
        for (int k2 = 0; k2 < 8; ++k2) {
            WgxH[q][k2] = pk(Wgx[q][k2][0], Wgx[q][k2][1]);
            WhH[q][k2]  = pk(Wh32[q][k2][0], Wh32[q][k2][1]);
        }

    h16x2 WoH[8];
    float bo = 0.0f;
#pragma unroll
    for (int k2 = 0; k2 < 8; ++k2) WoH[k2] = pk(0.0f, 0.0f);
    if (is_state) {
        f32x2 wo32[8];
        load_pairs16(W_out + j * 16, wo32);
#pragma unroll
        for (int k2 = 0; k2 < 8; ++k2) WoH[k2] = pk(wo32[k2][0], wo32[k2][1]);
        bo = b_out[j];
    }

    // ---- PIN: make weights asm-defined so they can't be remat-reloaded ----
#define PINH(x) do { int _t = __builtin_bit_cast(int, x); \
    asm volatile("" : "+v"(_t)); x = __builtin_bit_cast(h16x2, _t); } while (0)
#define PINF(x) asm volatile("" : "+v"(x))
#pragma unroll
    for (int q = 0; q < 4; ++q) {
#pragma unroll
        for (int k2 = 0; k2 < 8; ++k2) { PINH(WgxH[q][k2]); PINH(WhH[q][k2]); }
        PINF(sg[q]); PINF(cst[q]);
    }
#pragma unroll
    for (int k2 = 0; k2 < 8; ++k2) PINH(WoH[k2]);
    PINF(bo);

    const h16x2 one2 = pk(1.0f, 1.0f);

    // sincos partner: pairs (1,2),(3,4),(5,6) -- bpermute (R5-proven)
    int pj = j;
    if (j >= 1 && j <= 6) pj = ((j - 1) ^ 1) + 1;
    const int paddr = ((lane & 48) | pj) << 2;
    const bool donorm = (j >= 1 && j <= 6);

    // ---- per-stream state (plain variables only) ----
    h16x2 xpkA[8], hpkA[8], xpkB[8], hpkB[8];
    float stA, cA, muA, invA, cmdSA, cmdNA;
    float stB, cB, muB, invB, cmdSB, cmdNB;
    const float* cmdpA = commands + (size_t)bA * T * 4 + (j >= 12 ? j - 12 : 0);
    const float* cmdpB = commands + (size_t)bB * T * 4 + (j >= 12 ? j - 12 : 0);
    float* outpA = out + (size_t)bA * T * 12 + j;
    float* outpB = out + (size_t)bB * T * 12 + j;

    // DPP-packed-pair all-gather: lane n pairs with n^1 (quad_perm 0xB1),
    // even lanes hold pk(v_2i, v_2i+1); 8 bpermutes fetch the 8 pairs.
#define GATHPK(v, dstpk)                                                      \
    do {                                                                      \
        int _own = __float_as_int(v);                                         \
        int _par = dppi<0xB1>(_own);                                          \
        h16x2 _pp = pk(v, __int_as_float(_par));                              \
        int _ppi = __builtin_bit_cast(int, _pp);                              \
        _Pragma("unroll")                                                     \
        for (int _i = 0; _i < 8; ++_i)                                        \
            dstpk[_i] = __builtin_bit_cast(h16x2,                             \
                __builtin_amdgcn_ds_bpermute(gbase + (_i << 3), _ppi));       \
    } while (0)

#define PH_LN(S)                                                              \
    do {                                                                      \
        float _s0 = 0.f, _s1 = 0.f, _q0 = 0.f, _q1 = 0.f;                     \
        _Pragma("unroll")                                                     \
        for (int _i = 0; _i < 4; ++_i) {                                      \
            _s0 = fdot2(xpk##S[_i], one2, _s0);                               \
            _s1 = fdot2(xpk##S[_i + 4], one2, _s1);                           \
            _q0 = fdot2(xpk##S[_i], xpk##S[_i], _q0);                         \
            _q1 = fdot2(xpk##S[_i + 4], xpk##S[_i + 4], _q1);                 \
        }                                                                     \
        mu##S = (_s0 + _s1) * 0.0625f;                                        \
        float _var = (_q0 + _q1) * 0.0625f - mu##S * mu##S;                   \
        inv##S = __builtin_amdgcn_rsqf(_var + 1e-5f);                         \
    } while (0)

#define PH_GATES(S)                                                           \
    float hv##S;                                                              \
    do {                                                                      \
        float _gx0 = 0.f, _gx1 = 0.f, _gx2 = 0.f, _gx3 = 0.f;                 \
        float _gh0 = 0.f, _gh1 = 0.f, _gh2 = 0.f, _gh3 = 0.f;                 \
        _Pragma("unroll")                                                     \
        for (int _k = 0; _k < 8; ++_k) {                                      \
            _gx0 = fdot2(WgxH[0][_k], xpk##S[_k], _gx0);                      \
            _gx1 = fdot2(WgxH[1][_k], xpk##S[_k], _gx1);                      \
            _gx2 = fdot2(WgxH[2][_k], xpk##S[_k], _gx2);                      \
            _gx3 = fdot2(WgxH[3][_k], xpk##S[_k], _gx3);                      \
            _gh0 = fdot2(WhH[0][_k], hpk##S[_k], _gh0);                       \
            _gh1 = fdot2(WhH[1][_k], hpk##S[_k], _gh1);                       \
            _gh2 = fdot2(WhH[2][_k], hpk##S[_k], _gh2);                       \
            _gh3 = fdot2(WhH[3][_k], hpk##S[_k], _gh3);                       \
        }                                                                     \
        float _nmi = -mu##S * inv##S;                                         \
        float _gi = __builtin_fmaf(_gx0, inv##S, __builtin_fmaf(_nmi, sg[0], cst[0] + _gh0)); \
        float _gf = __builtin_fmaf(_gx1, inv##S, __builtin_fmaf(_nmi, sg[1], cst[1] + _gh1)); \
        float _gG = __builtin_fmaf(_gx2, inv##S, __builtin_fmaf(_nmi, sg[2], cst[2] + _gh2)); \
        float _go = __builtin_fmaf(_gx3, inv##S, __builtin_fmaf(_nmi, sg[3], cst[3] + _gh3)); \
        float _iv = sigmoid_fast(_gi);                                        \
        float _fv = sigmoid_fast(_gf);                                        \
        float _gv = tanh_fast(_gG);                                           \
        float _ov = sigmoid_fast(_go);                                        \
        c##S = _fv * c##S + _iv * _gv;                                        \
        hv##S = _ov * tanh_fast(c##S);                                        \
    } while (0)

#define PH_WOUT(S, STPRED)                                                    \
    do {                                                                      \
        float _o0 = 0.f, _o1 = 0.f;                                           \
        _Pragma("unroll")                                                     \
        for (int _k = 0; _k < 4; ++_k) {                                      \
            _o0 = fdot2(WoH[_k], hpk##S[_k], _o0);                            \
            _o1 = fdot2(WoH[_k + 4], hpk##S[_k + 4], _o1);                    \
        }                                                                     \
        float _sraw = st##S + (_o0 + _o1) + bo;                               \
        float _pv = __int_as_float(                                           \
            __builtin_amdgcn_ds_bpermute(paddr, __float_as_int(_sraw)));      \
        float _nrm = __builtin_amdgcn_sqrtf(_sraw * _sraw + _pv * _pv) + 1e-8f; \
        float _stn = _sraw * rcp_fast(_nrm);                                  \
        st##S = donorm ? _stn : _sraw;                                        \
        if (STPRED) outp##S[0] = st##S;                                       \
        outp##S += 12;                                                        \
    } while (0)

#define PH_XGATH(S)                                                           \
    do {                                                                      \
        float _xv = is_state ? st##S : cmdS##S;                               \
        GATHPK(_xv, xpk##S);                                                  \
    } while (0)

#define PH_CMD(S, tt)                                                         \
    do {                                                                      \
        cmdS##S = cmdN##S;                                                    \
        int _tn = (tt) + 3;                                                   \
        if (_tn > T - 1) _tn = T - 1;                                         \
        if (j >= 12) cmdN##S = cmdp##S[(size_t)_tn * 4];                      \
    } while (0)

#define INIT_STREAM(S, BS)                                                    \
    do {                                                                      \
        st##S = is_state ? init_state[(BS) * 12 + j] : 0.0f;                  \
        c##S = 0.0f;                                                          \
        _Pragma("unroll")                                                     \
        for (int _k = 0; _k < 8; ++_k) hpk##S[_k] = pk(0.0f, 0.0f);           \
        float _cmd0 = (j >= 12) ? cmdp##S[0] : 0.0f;                          \
        float _xv = is_state ? st##S : _cmd0;                                 \
        GATHPK(_xv, xpk##S);                                                  \
        PH_LN(S);                                                             \
        cmdS##S = (j >= 12) ? cmdp##S[(size_t)(T > 1 ? 1 : 0) * 4] : 0.0f;    \
        cmdN##S = (j >= 12) ? cmdp##S[(size_t)(T > 2 ? 2 : 0) * 4] : 0.0f;    \
    } while (0)

    INIT_STREAM(A, bA);
    INIT_STREAM(B, bB);

    const bool predA = (lane < 32) && is_state;
    const bool predB = (lane >= 32) && is_state;

    for (int t = 0; t < T; ++t) {
        PH_GATES(A);
        PH_GATES(B);
        GATHPK(hvA, hpkA);
        GATHPK(hvB, hpkB);
        PH_WOUT(A, predA);
        PH_WOUT(B, predB);
        PH_XGATH(A);
        PH_XGATH(B);
        PH_LN(A);
        PH_LN(B);
        PH_CMD(A, t);
        PH_CMD(B, t);
    }

#undef PINH
#undef PINF
#undef GATHPK
#undef PH_LN
#undef PH_GATES
#undef PH_WOUT
#undef PH_XGATH
#undef PH_CMD
#undef INIT_STREAM
}

extern "C" void kernel_launch(void* const* d_in, const int* in_sizes, int n_in,
                              void* d_out, int out_size, void* d_ws, size_t ws_size,
                              hipStream_t stream) {
    const float* init_state = (const float*)d_in[0];
    const float* commands   = (const float*)d_in[1];
    const float* ln_g       = (const float*)d_in[2];
    const float* ln_b       = (const float*)d_in[3];
    const float* W_in       = (const float*)d_in[4];
    const float* b_in       = (const float*)d_in[5];
    const float* W_ih       = (const float*)d_in[6];
    const float* W_hh       = (const float*)d_in[7];
    const float* b_ih       = (const float*)d_in[8];
    const float* b_hh       = (const float*)d_in[9];
    const float* W_out      = (const float*)d_in[10];
    const float* b_out      = (const float*)d_in[11];

    int B = in_sizes[0] / 12;           // 8192
    int T = in_sizes[1] / (B * 4);      // 256

    int blocks = B / 4;                 // 4 batches per wave (2 per stream)
    vm_kernel<<<blocks, 64, 0, stream>>>(init_state, commands, ln_g, ln_b,
                                         W_in, b_in, W_ih, W_hh, b_ih, b_hh,
                                         W_out, b_out, (float*)d_out, B, T);
}

// Round 8
// 320.456 us; speedup vs baseline: 1.7052x; 1.7052x over previous
//
#include <hip/hip_runtime.h>

typedef float f32x2 __attribute__((ext_vector_type(2)));
typedef float f32x4 __attribute__((ext_vector_type(4)));
typedef _Float16 f16x4 __attribute__((ext_vector_type(4)));
typedef __fp16 fp16x2_raw __attribute__((ext_vector_type(2)));
typedef __fp16 fp16x4_raw __attribute__((ext_vector_type(4)));

#define LOG2E 1.44269504088896340736f

static __device__ __forceinline__ float rcp_fast(float x) { return __builtin_amdgcn_rcpf(x); }

static __device__ __forceinline__ f32x2 mk2(float a, float b) { f32x2 v; v[0] = a; v[1] = b; return v; }

static __device__ __forceinline__ float sigmoid_fast(float x) {
    return rcp_fast(1.0f + __builtin_amdgcn_exp2f(-LOG2E * x));
}

static __device__ __forceinline__ float tanh_fast(float x) {
    float a = __builtin_fabsf(x);
    float t = __builtin_amdgcn_exp2f(-2.0f * LOG2E * a);
    float r = (1.0f - t) * rcp_fast(1.0f + t);
    return __builtin_copysignf(r, x);
}

// pack 4 f32 -> 4 f16 (one B/A fragment for mfma 16x16x16 f16)
static __device__ __forceinline__ f16x4 pk4(float a, float b, float c, float d) {
    fp16x2_raw lo = __builtin_amdgcn_cvt_pkrtz(a, b);
    fp16x2_raw hi = __builtin_amdgcn_cvt_pkrtz(c, d);
    fp16x4_raw r = __builtin_shufflevector(lo, hi, 0, 1, 2, 3);
    return __builtin_bit_cast(f16x4, r);
}

static __device__ __forceinline__ float swz16(float v) {  // lane ^ 16 (within 32-halves)
    return __int_as_float(__builtin_amdgcn_ds_swizzle(__float_as_int(v), 0x401F));
}
static __device__ __forceinline__ float bperm(int addr, float v) {
    return __int_as_float(__builtin_amdgcn_ds_bpermute(addr, __float_as_int(v)));
}

static __device__ __forceinline__ void load_pairs16(const float* p, f32x2* dst) {
    const f32x4* q4 = (const f32x4*)p;
    f32x4 a = q4[0], b = q4[1], c = q4[2], d = q4[3];
    dst[0] = __builtin_shufflevector(a, a, 0, 1);
    dst[1] = __builtin_shufflevector(a, a, 2, 3);
    dst[2] = __builtin_shufflevector(b, b, 0, 1);
    dst[3] = __builtin_shufflevector(b, b, 2, 3);
    dst[4] = __builtin_shufflevector(c, c, 0, 1);
    dst[5] = __builtin_shufflevector(c, c, 2, 3);
    dst[6] = __builtin_shufflevector(d, d, 0, 1);
    dst[7] = __builtin_shufflevector(d, d, 2, 3);
}

#define MFMA16(A, B, C) __builtin_amdgcn_mfma_f32_16x16x16f16(A, B, C, 0, 0, 0)
// select f32x2 pair {2g+half} from an 8-pair row (k-block of this lane's group)
#define KSEL(W, half) ((g & 2) ? ((g & 1) ? (W)[6 + (half)] : (W)[4 + (half)]) \
                               : ((g & 1) ? (W)[2 + (half)] : (W)[0 + (half)]))

// MFMA formulation: one wave = 16 batches. Lane l: b = l&15 (batch / B-col /
// D-col), g = l>>4 (k-group / D-row-group). Per step:
//   gates[64x16b] : 8 MFMA  (q=0..3: D=Wh_q@h + (Wgx_q@x_ln + Cbias))
//   state  update : 1 MFMA  (D=Wo@h + (st+bo)),  rows 12..15 zero-padded
// KEY: D rows (g*4+r) == B k-slots (g*4+e), so h (from activations) and state
// (from the Wout MFMA) are ALREADY in next-step B-fragment position -- zero
// cross-lane redistribution. Only LN stats (2 swizzle + 2 bpermute) and the
// (3,4) sincos pair (1 swizzle) cross lanes. LN feeds x_ln=(x-mu)*inv with the
// R1-verified W_in/gamma/beta fold (bias enters via the MFMA C operand).
__global__ __launch_bounds__(64) void vm_kernel(
    const float* __restrict__ init_state,  // (B,1,12)
    const float* __restrict__ commands,    // (B,T,4)
    const float* __restrict__ ln_g,        // (16)
    const float* __restrict__ ln_b,        // (16)
    const float* __restrict__ W_in,        // (16,16)
    const float* __restrict__ b_in,        // (16)
    const float* __restrict__ W_ih,        // (64,16)
    const float* __restrict__ W_hh,        // (64,16)
    const float* __restrict__ b_ih,        // (64)
    const float* __restrict__ b_hh,        // (64)
    const float* __restrict__ W_out,       // (12,16)
    const float* __restrict__ b_out,       // (12)
    float* __restrict__ out,               // (B,T,12)
    int B, int T)
{
    const int lane = threadIdx.x;
    const int j = lane & 15;                  // fold row AND batch column
    const int g = lane >> 4;                  // k-group / row-group
    const int bg = blockIdx.x * 16 + j;       // global batch
    const int pa32 = (lane ^ 32) << 2;        // bpermute addr: other 32-half

    // ---- preamble: gate-weight fold (identical math to verified R1/R5) ----
    f32x2 Wih[4][8], Wh32[4][8];
#pragma unroll
    for (int q = 0; q < 4; ++q) {
        load_pairs16(W_ih + (q * 16 + j) * 16, Wih[q]);
        load_pairs16(W_hh + (q * 16 + j) * 16, Wh32[q]);
    }
    f32x2 Wgx[4][8];
    float binacc[4];
#pragma unroll
    for (int q = 0; q < 4; ++q) {
        binacc[q] = 0.0f;
#pragma unroll
        for (int k2 = 0; k2 < 8; ++k2) Wgx[q][k2] = mk2(0.0f, 0.0f);
    }
#pragma unroll
    for (int m = 0; m < 16; ++m) {
        f32x2 wm[8];
        load_pairs16(W_in + m * 16, wm);
        float bm = b_in[m];
#pragma unroll
        for (int q = 0; q < 4; ++q) {
            float wim = Wih[q][m >> 1][m & 1];
            f32x2 w2 = mk2(wim, wim);
#pragma unroll
            for (int k2 = 0; k2 < 8; ++k2) Wgx[q][k2] += w2 * wm[k2];
            binacc[q] += wim * bm;
        }
    }
    float cst[4];
    {
        f32x2 gg2[8], bt2[8];
        load_pairs16(ln_g, gg2);
        load_pairs16(ln_b, bt2);
#pragma unroll
        for (int q = 0; q < 4; ++q) {
            f32x2 cc2 = mk2(0.0f, 0.0f);
#pragma unroll
            for (int k2 = 0; k2 < 8; ++k2) {
                cc2 += Wgx[q][k2] * bt2[k2];   // beta applied to pre-gamma W_eff
                Wgx[q][k2] *= gg2[k2];         // gamma folded into W_eff
            }
            cst[q] = cc2[0] + cc2[1] + binacc[q] + b_ih[q * 16 + j] + b_hh[q * 16 + j];
        }
    }

    // ---- A fragments: lane row i=j, k-block g (KSEL), packed to f16 ----
    f16x4 Ax[4], Ah[4];
#pragma unroll
    for (int q = 0; q < 4; ++q) {
        f32x2 p0 = KSEL(Wgx[q], 0), p1 = KSEL(Wgx[q], 1);
        Ax[q] = pk4(p0[0], p0[1], p1[0], p1[1]);
        f32x2 h0 = KSEL(Wh32[q], 0), h1 = KSEL(Wh32[q], 1);
        Ah[q] = pk4(h0[0], h0[1], h1[0], h1[1]);
    }
    f16x4 Awo;
    {
        f32x2 wo[8];
#pragma unroll
        for (int k2 = 0; k2 < 8; ++k2) wo[k2] = mk2(0.0f, 0.0f);
        if (j < 12) load_pairs16(W_out + j * 16, wo);   // rows 12..15 zero
        f32x2 p0 = KSEL(wo, 0), p1 = KSEL(wo, 1);
        Awo = pk4(p0[0], p0[1], p1[0], p1[1]);
    }

    // ---- bias redistribution: cst_q[j] -> biasv[q][r]=cst_q[g*4+r] (LDS) ----
    __shared__ float cstL[4][16];
    if (lane < 16) {
        cstL[0][j] = cst[0]; cstL[1][j] = cst[1];
        cstL[2][j] = cst[2]; cstL[3][j] = cst[3];
    }
    __syncthreads();
    f32x4 biasv[4];
#pragma unroll
    for (int q = 0; q < 4; ++q)
#pragma unroll
        for (int r = 0; r < 4; ++r) biasv[q][r] = cstL[q][g * 4 + r];

    const int gg = (g < 3) ? g : 0;
    f32x4 boV = *(const f32x4*)(b_out + gg * 4);        // g3: dead rows
    f32x4 stv = *(const f32x4*)(init_state + (size_t)bg * 12 + gg * 4);

    const f32x4* cmd4 = (const f32x4*)(commands + (size_t)bg * T * 4);
    float* outp = out + (size_t)bg * T * 12 + g * 4;
    const bool isg3 = (g == 3);

    f32x4 cmdS = {0.f, 0.f, 0.f, 0.f}, cmdN = {0.f, 0.f, 0.f, 0.f};
    if (isg3) {
        f32x4 c0 = cmd4[0];
        stv = c0;                                       // x0 cmd slots
        cmdS = cmd4[(T > 1) ? 1 : 0];
        cmdN = cmd4[(T > 2) ? 2 : 0];
    }

    // LN -> x fragment (x_ln = (x-mu)*inv); stats over 4 groups of batch b
#define LN_XFRAG(xf)                                                          \
    do {                                                                      \
        float _ps = (stv[0] + stv[1]) + (stv[2] + stv[3]);                    \
        float _pq = ((stv[0] * stv[0] + stv[1] * stv[1]) +                    \
                     (stv[2] * stv[2] + stv[3] * stv[3]));                    \
        _ps += swz16(_ps); _pq += swz16(_pq);                                 \
        _ps += bperm(pa32, _ps); _pq += bperm(pa32, _pq);                     \
        float _mu = _ps * 0.0625f;                                            \
        float _var = _pq * 0.0625f - _mu * _mu;                               \
        float _inv = __builtin_amdgcn_rsqf(_var + 1e-5f);                     \
        float _nmi = -_mu * _inv;                                             \
        xf = pk4(__builtin_fmaf(stv[0], _inv, _nmi),                          \
                 __builtin_fmaf(stv[1], _inv, _nmi),                          \
                 __builtin_fmaf(stv[2], _inv, _nmi),                          \
                 __builtin_fmaf(stv[3], _inv, _nmi));                         \
    } while (0)

    f16x4 xfrag, hfrag = pk4(0.f, 0.f, 0.f, 0.f);
    LN_XFRAG(xfrag);

    f32x4 cc = {0.f, 0.f, 0.f, 0.f};   // LSTM c for j=g*4+r of batch b

    for (int t = 0; t < T; ++t) {
        // ---- 8 gate MFMAs (bias seeded via C) ----
        f32x4 a0 = MFMA16(Ax[0], xfrag, biasv[0]);
        f32x4 a1 = MFMA16(Ax[1], xfrag, biasv[1]);
        f32x4 a2 = MFMA16(Ax[2], xfrag, biasv[2]);
        f32x4 a3 = MFMA16(Ax[3], xfrag, biasv[3]);
        a0 = MFMA16(Ah[0], hfrag, a0);
        a1 = MFMA16(Ah[1], hfrag, a1);
        a2 = MFMA16(Ah[2], hfrag, a2);
        a3 = MFMA16(Ah[3], hfrag, a3);

        // ---- activations (4 cells per lane, all local) ----
        float hv0, hv1, hv2, hv3;
        {
            float iv, fv, gv, ov;
            iv = sigmoid_fast(a0[0]); fv = sigmoid_fast(a1[0]);
            gv = tanh_fast(a2[0]);    ov = sigmoid_fast(a3[0]);
            cc[0] = fv * cc[0] + iv * gv; hv0 = ov * tanh_fast(cc[0]);
            iv = sigmoid_fast(a0[1]); fv = sigmoid_fast(a1[1]);
            gv = tanh_fast(a2[1]);    ov = sigmoid_fast(a3[1]);
            cc[1] = fv * cc[1] + iv * gv; hv1 = ov * tanh_fast(cc[1]);
            iv = sigmoid_fast(a0[2]); fv = sigmoid_fast(a1[2]);
            gv = tanh_fast(a2[2]);    ov = sigmoid_fast(a3[2]);
            cc[2] = fv * cc[2] + iv * gv; hv2 = ov * tanh_fast(cc[2]);
            iv = sigmoid_fast(a0[3]); fv = sigmoid_fast(a1[3]);
            gv = tanh_fast(a2[3]);    ov = sigmoid_fast(a3[3]);
            cc[3] = fv * cc[3] + iv * gv; hv3 = ov * tanh_fast(cc[3]);
        }
        hfrag = pk4(hv0, hv1, hv2, hv3);   // already B-fragment layout!

        // ---- state update MFMA: D = Wo@h + (st + bo) ----
        f32x4 cw;
        cw[0] = stv[0] + boV[0]; cw[1] = stv[1] + boV[1];
        cw[2] = stv[2] + boV[2]; cw[3] = stv[3] + boV[3];
        f32x4 so = MFMA16(Awo, hfrag, cw);

        // ---- sincos renorm: pairs (1,2) g0-local, (5,6) g1-local, (3,4) x-lane
        float s0 = so[0], s1 = so[1], s2 = so[2], s3 = so[3];
        float ex = (g == 1) ? s0 : s3;          // g0 sends st3, g1 sends st4
        float px = swz16(ex);
        bool g01 = (g <= 1);
        float r12 = rcp_fast(__builtin_amdgcn_sqrtf(s1 * s1 + s2 * s2) + 1e-8f);
        s1 = g01 ? s1 * r12 : s1;
        s2 = g01 ? s2 * r12 : s2;
        float aa = (g == 1) ? s0 : s3;
        float rcr = rcp_fast(__builtin_amdgcn_sqrtf(aa * aa + px * px) + 1e-8f);
        s3 = (g == 0) ? s3 * rcr : s3;
        s0 = (g == 1) ? s0 * rcr : s0;

        // ---- store (state rows only) ----
        if (g < 3) {
            f32x4 ov4; ov4[0] = s0; ov4[1] = s1; ov4[2] = s2; ov4[3] = s3;
            *(f32x4*)outp = ov4;
        }
        outp += 12;

        // ---- next x: state (g<3) / next cmd (g3); LN -> fragment ----
        f32x4 nx; nx[0] = s0; nx[1] = s1; nx[2] = s2; nx[3] = s3;
        if (isg3) nx = cmdS;
        stv = nx;
        LN_XFRAG(xfrag);

        // rotate 2-deep cmd prefetch
        cmdS = cmdN;
        int tn = t + 3;
        if (tn > T - 1) tn = T - 1;
        if (isg3) cmdN = cmd4[tn];
    }
#undef LN_XFRAG
}

extern "C" void kernel_launch(void* const* d_in, const int* in_sizes, int n_in,
                              void* d_out, int out_size, void* d_ws, size_t ws_size,
                              hipStream_t stream) {
    const float* init_state = (const float*)d_in[0];
    const float* commands   = (const float*)d_in[1];
    const float* ln_g       = (const float*)d_in[2];
    const float* ln_b       = (const float*)d_in[3];
    const float* W_in       = (const float*)d_in[4];
    const float* b_in       = (const float*)d_in[5];
    const float* W_ih       = (const float*)d_in[6];
    const float* W_hh       = (const float*)d_in[7];
    const float* b_ih       = (const float*)d_in[8];
    const float* b_hh       = (const float*)d_in[9];
    const float* W_out      = (const float*)d_in[10];
    const float* b_out      = (const float*)d_in[11];

    int B = in_sizes[0] / 12;           // 8192
    int T = in_sizes[1] / (B * 4);      // 256

    int blocks = B / 16;                // 16 batches per 64-thread wave
    vm_kernel<<<blocks, 64, 0, stream>>>(init_state, commands, ln_g, ln_b,
                                         W_in, b_in, W_ih, W_hh, b_ih, b_hh,
                                         W_out, b_out, (float*)d_out, B, T);
}